// Round 8
// baseline (95.138 us; speedup 1.0000x reference)
//
#include <hip/hip_runtime.h>
#include <stdint.h>

typedef float  f32x4 __attribute__((ext_vector_type(4)));
typedef short  s16x8 __attribute__((ext_vector_type(8)));
typedef unsigned short u16;

#define KK 32768   /* NN*DD */

__device__ __forceinline__ u16 f2bf_rn(float f) {
  uint32_t u = __float_as_uint(f);
  u += 0x7fffu + ((u >> 16) & 1u);
  return (u16)(u >> 16);
}
__device__ __forceinline__ float bf2f(u16 h) {
  return __uint_as_float(((uint32_t)h) << 16);
}

// global -> LDS direct DMA, 16B per lane. LDS dest = wave-uniform base + lane*16.
__device__ __forceinline__ void gload_lds16(const void* g, void* l) {
  __builtin_amdgcn_global_load_lds(
      (const __attribute__((address_space(1))) uint32_t*)g,
      (__attribute__((address_space(3))) uint32_t*)l, 16, 0, 0);
}

// ---------------------------------------------------------------------------
// Kernel A: g_t[b][c][k] = x[b,s,c] * W[d,c], k = s*32+d, LINEAR layout
// (the GEMM's B-stage applies its LDS swizzle via per-lane source addresses).
// bf16 hi/lo planes.
// ---------------------------------------------------------------------------
__global__ void build_g(const float* __restrict__ x, const float* __restrict__ W,
                        u16* __restrict__ ghi, u16* __restrict__ glo) {
  int t  = blockIdx.x * 256 + threadIdx.x;
  int k0 = (t & 4095) << 3;
  int c  = (t >> 12) & 63;
  int b  = t >> 18;
  int s  = k0 >> 5;
  int d0 = k0 & 31;
  float xv = x[(((b << 10) + s) << 6) + c];
  s16x8 vh, vl;
#pragma unroll
  for (int i = 0; i < 8; ++i) {
    float g = xv * W[((d0 + i) << 6) + c];
    u16 h = f2bf_rn(g);
    vh[i] = (short)h;
    vl[i] = (short)f2bf_rn(g - bf2f(h));
  }
  size_t off = (((size_t)((b << 6) + c)) << 15) + (size_t)k0;
  *reinterpret_cast<s16x8*>(ghi + off) = vh;
  *reinterpret_cast<s16x8*>(glo + off) = vl;
}

// ---------------------------------------------------------------------------
// Kernel B: B-persistent split-K GEMM. Grid (1,128,2) = 256 WGs (1/CU),
// 512 threads = 8 waves (4 row-groups x 2 col-halves).
// Each WG: k-window [ks*256, +256). B (hi/lo, 64KB, XOR-swizzled) staged to
// LDS ONCE; A quad-buffered 4x16KB, depth-2 prefetch, counted vmcnt (exact
// accounting including part-stores); ONE barrier per step. 64 steps
// (16 m-tiles x 4). 3-product split-bf16 MFMA, fp32 acc.
// LDS (128KB): A[q] q*16KB (q=u&3) | B at 64KB: [plane][c][512B].
// ---------------------------------------------------------------------------
#define MFMA16(A_, B_, C_) __builtin_amdgcn_mfma_f32_16x16x32_bf16((A_), (B_), (C_), 0, 0, 0)

__global__ __launch_bounds__(512) void gemm_bpers(
    const float* __restrict__ kb, const u16* __restrict__ ghi,
    const u16* __restrict__ glo, float* __restrict__ part) {
  __shared__ unsigned char lds[131072];

  const int tid = threadIdx.x;
  const int w   = tid >> 6;      // wave 0..7
  const int l   = tid & 63;
  const int lr  = l & 15;
  const int lk  = l >> 4;
  const int ks  = blockIdx.y;    // 0..127 k-window
  const int b   = blockIdx.z;
  const int k0  = ks << 8;       // *256 elements

  // ---- B persistent stage (8 instrs/thread, 64KB total), swizzled source --
  // instr j: P=j*8192+tid*16; plane=j>>2; c=(j&3)*16+(tid>>5); kbyte=(tid&31)<<4
  // stored-at kbyte holds source kbyte ^ ((c&7)<<4).
#pragma unroll
  for (int j = 0; j < 8; ++j) {
    int plane = j >> 2;
    int c     = ((j & 3) << 4) + (tid >> 5);
    int kbs   = ((tid & 31) << 4) ^ ((c & 7) << 4);
    const u16* src = (plane ? glo : ghi)
                   + (((size_t)((b << 6) + c)) << 15) + k0 + (kbs >> 1);
    gload_lds16(src, lds + 65536 + j * 8192 + (w << 10));
  }

  // ---- A staging constants: instr i in {0,1}: row=i*32+(tid>>4), cs=(tid&15)<<4
  const float* abp[2]; int adst[2];
#pragma unroll
  for (int i = 0; i < 2; ++i) {
    int row  = i * 32 + (tid >> 4);
    int csrc = ((tid & 15) << 4) ^ ((row & 7) << 4);
    abp[i]  = kb + (((size_t)((b << 10) + row)) << 15) + k0 + (csrc >> 2);
    adst[i] = i * 8192 + (w << 10);
  }

  const int rg   = w >> 1;                 // row-group 0..3
  const int ch   = w & 1;                  // col-half 0..1
  const int arow = (rg << 4) + lr;
  const int abo  = arow << 8;              // arow*256 within A buffer
  const int aswz = (arow & 7) << 4;
  const int ch32 = ch << 5;

  f32x4 acc0 = {0,0,0,0}, acc1 = {0,0,0,0};

  auto STAGE_A = [&](int u2) {
    size_t moff = ((size_t)(u2 >> 2) << 21) + (size_t)((u2 & 3) << 6); // mt*64rows + ts*64k
    int qb = (u2 & 3) * 16384;
#pragma unroll
    for (int i = 0; i < 2; ++i)
      gload_lds16(abp[i] + moff, lds + qb + adst[i]);
  };

  STAGE_A(0);
  STAGE_A(1);

  const int NT = 64;
  for (int u = 0; u < NT; ++u) {
    if (u + 2 < NT) STAGE_A(u + 2);
    // counted wait for A(u) (B is older -> also landed at u=0).
    // younger-than-A(u): A(u+1),A(u+2) (+8 part-stores when u%4 in {0,1}, u>=4)
    if (u == NT - 1)                     { asm volatile("s_waitcnt vmcnt(0)" ::: "memory"); }
    else if (u == NT - 2)                { asm volatile("s_waitcnt vmcnt(2)" ::: "memory"); }
    else if (u >= 4 && (u & 2) == 0)     { asm volatile("s_waitcnt vmcnt(12)" ::: "memory"); }
    else                                 { asm volatile("s_waitcnt vmcnt(4)" ::: "memory"); }
    __builtin_amdgcn_sched_barrier(0);
    __builtin_amdgcn_s_barrier();
    __builtin_amdgcn_sched_barrier(0);

    const int q  = u & 3;                // A buffer AND within-mt step (period 4)
    const unsigned char* LA = lds + q * 16384;

#pragma unroll
    for (int kb2 = 0; kb2 < 2; ++kb2) {
      int ac = (kb2 << 7) + (lk << 5);
      f32x4 a0 = *reinterpret_cast<const f32x4*>(LA + abo + ( ac       ^ aswz));
      f32x4 a1 = *reinterpret_cast<const f32x4*>(LA + abo + ((ac + 16) ^ aswz));
      s16x8 ah, al;
#pragma unroll
      for (int i = 0; i < 8; ++i) {
        float f = (i < 4) ? a0[i] : a1[i - 4];
        uint32_t uu = __float_as_uint(f);
        ah[i] = (short)(u16)(uu >> 16);
        al[i] = (short)f2bf_rn(f - __uint_as_float(uu & 0xffff0000u));
      }
      int kbyte = (q << 7) + (kb2 << 6) + (lk << 4);  // ts*128 + ...
#pragma unroll
      for (int j2 = 0; j2 < 2; ++j2) {
        int c  = ch32 + (j2 << 4) + lr;
        int bo = 65536 + (c << 9) + (kbyte ^ ((c & 7) << 4));
        s16x8 bh = *reinterpret_cast<const s16x8*>(lds + bo);
        s16x8 bl = *reinterpret_cast<const s16x8*>(lds + bo + 32768);
        f32x4& A_ = j2 ? acc1 : acc0;
        A_ = MFMA16(ah, bh, A_);
        A_ = MFMA16(al, bh, A_);
        A_ = MFMA16(ah, bl, A_);
      }
    }

    if (q == 3) {                        // end of m-tile: flush 8 stores/wave
      int mt = u >> 2;
      float* pb = part + (((size_t)((b << 7) + ks)) << 16);
#pragma unroll
      for (int j2 = 0; j2 < 2; ++j2) {
        const f32x4& A_ = j2 ? acc1 : acc0;
#pragma unroll
        for (int i = 0; i < 4; ++i) {
          int rr = (mt << 6) + (rg << 4) + (lk << 2) + i;
          int cc = ch32 + (j2 << 4) + lr;
          pb[((size_t)rr << 6) + cc] = A_[i];
        }
      }
      acc0 = f32x4{0,0,0,0};
      acc1 = f32x4{0,0,0,0};
    }
  }
}

// ---------------------------------------------------------------------------
// Kernel C: per (b,r): reduce Sk partials + conv_bias -> LayerNorm -> MLP.
// ---------------------------------------------------------------------------
__device__ __forceinline__ float gelu_tanh(float v) {
  float u = 0.7978845608028654f * (v + 0.044715f * v * v * v);
  float e = __expf(2.0f * u);
  float th = 1.0f - 2.0f / (e + 1.0f);
  return 0.5f * v * (1.0f + th);
}

__global__ __launch_bounds__(256) void epilogue(
    const float* __restrict__ part, const float* __restrict__ conv_bias,
    const float* __restrict__ ln_scale, const float* __restrict__ ln_bias,
    const float* __restrict__ W1, const float* __restrict__ b1,
    const float* __restrict__ W2, const float* __restrict__ b2,
    float* __restrict__ out, int Sk) {
  __shared__ float red[4][64];
  __shared__ float nbuf[64];
  __shared__ float hbuf[256];

  const int tid = threadIdx.x;
  const int b = blockIdx.x >> 10;
  const int r = blockIdx.x & 1023;
  const int c = tid & 63;
  const int q = tid >> 6;

  float s = 0.0f;
  for (int ks = q; ks < Sk; ks += 4)
    s += part[(((size_t)(b * Sk + ks)) << 16) + ((size_t)r << 6) + c];
  red[q][c] = s;
  __syncthreads();

  if (q == 0) {
    float a = red[0][c] + red[1][c] + red[2][c] + red[3][c] + conv_bias[c];
    float sum = a;
#pragma unroll
    for (int off = 32; off >= 1; off >>= 1) sum += __shfl_xor(sum, off);
    float mu = sum * (1.0f / 64.0f);
    float d = a - mu;
    float ss = d * d;
#pragma unroll
    for (int off = 32; off >= 1; off >>= 1) ss += __shfl_xor(ss, off);
    float var = ss * (1.0f / 64.0f);
    nbuf[c] = d * rsqrtf(var + 1e-6f) * ln_scale[c] + ln_bias[c];
  }
  __syncthreads();

  {
    float acc = b1[tid];
#pragma unroll 8
    for (int cc = 0; cc < 64; ++cc) acc += nbuf[cc] * W1[(cc << 8) + tid];
    hbuf[tid] = gelu_tanh(acc);
  }
  __syncthreads();

  {
    float po = 0.0f;
#pragma unroll 8
    for (int jj = 0; jj < 64; ++jj) {
      int j = (q << 6) + jj;
      po += hbuf[j] * W2[(j << 6) + c];
    }
    red[q][c] = po;
  }
  __syncthreads();
  if (tid < 64) {
    float o = red[0][c] + red[1][c] + red[2][c] + red[3][c] + b2[c];
    out[(((size_t)(b << 10) + r) << 6) + c] = o;
  }
}

// ---------------------------------------------------------------------------
extern "C" void kernel_launch(void* const* d_in, const int* in_sizes, int n_in,
                              void* d_out, int out_size, void* d_ws, size_t ws_size,
                              hipStream_t stream) {
  const float* x         = (const float*)d_in[0];
  const float* kb        = (const float*)d_in[1];
  const float* kernel_W  = (const float*)d_in[2];
  const float* conv_bias = (const float*)d_in[3];
  const float* ln_scale  = (const float*)d_in[4];
  const float* ln_bias   = (const float*)d_in[5];
  const float* W1        = (const float*)d_in[6];
  const float* b1        = (const float*)d_in[7];
  const float* W2        = (const float*)d_in[8];
  const float* b2        = (const float*)d_in[9];
  float* out = (float*)d_out;

  // Workspace layout (needs 84 MB; harness provides ~1 GB):
  //   ghi 8.4MB | glo 8.4MB | part 128*2*256KB = 67MB
  char* wsb = (char*)d_ws;
  u16* ghi = (u16*)wsb;
  u16* glo = (u16*)(wsb + 8388608);
  float* part = (float*)(wsb + 16777216);
  const int Sk = 128;   // fixed: one 256-k window per WG, 256 WGs = 1/CU

  build_g<<<2048, 256, 0, stream>>>(x, kernel_W, ghi, glo);
  gemm_bpers<<<dim3(1, Sk, 2), 512, 0, stream>>>(kb, ghi, glo, part);
  epilogue<<<dim3(2048), 256, 0, stream>>>(part, conv_bias, ln_scale, ln_bias,
                                           W1, b1, W2, b2, out, Sk);
}